// Round 11
// baseline (322.055 us; speedup 1.0000x reference)
//
#include <hip/hip_runtime.h>
#include <math.h>

#define VOCAB 32000
#define BATCH 16
#define SEQ   512
#define RPL   8           // DP rows per lane in editdist
#define NED   16          // consumer blocks (one per batch)
#define NAMX  1024        // producer blocks (4 waves, 2 rows per wave)
#define NBLK  125         // 1KB wave-blocks per row

typedef float floatx4 __attribute__((ext_vector_type(4)));

// ---------------------------------------------------------------------------
// init: zero word flags (0 = not ready) and out[0].
// ---------------------------------------------------------------------------
__global__ void init_kernel(int* __restrict__ words, float* __restrict__ out) {
    int g = blockIdx.x * 256 + threadIdx.x;
    if (g < BATCH * SEQ) words[g] = 0;
    if (g == 0) out[0] = 0.0f;
}

// ---------------------------------------------------------------------------
// Fused producer/consumer.
//  blocks 0..15     : editdist consumer, batch b = blockIdx.x (wave 0 only).
//  blocks 16..1039  : argmax producer, j-major row order (phase 0: j<256,
//                     phase 1: j>=256) so words complete in j-order halves.
// R5 regressed because same-j bursts hit identical channel bits (rows 64MiB
// apart). Fix: per-row circular start stagger (row*53 % 125, 11KB offset
// between same-j streams of adjacent batches) — R7 proved stagger is free.
// 1040 blocks * 4 waves = 4160 waves, all co-resident (cap 8192): consumers
// are dispatched first and can never deadlock producers.
// ---------------------------------------------------------------------------
__global__ __launch_bounds__(256) void fused_kernel(const float* __restrict__ logits,
                                                    const int* __restrict__ target,
                                                    int* __restrict__ words,
                                                    float* __restrict__ out) {
    const int wid  = threadIdx.x >> 6;
    const int lane = threadIdx.x & 63;

    if (blockIdx.x < NED) {
        // ================= editdist consumer =================
        if (wid != 0) return;                  // wave 0 only
        const int b = blockIdx.x;
        const int t = lane;

        // lane t owns TARGET rows t*8+1..t*8+8 (edit distance is symmetric)
        int myt[RPL];
        #pragma unroll
        for (int r = 0; r < RPL; ++r)
            myt[r] = target[b * SEQ + t * RPL + r] + 1;   // +1 matches stored idx+1

        int colv[RPL];
        #pragma unroll
        for (int r = 0; r < RPL; ++r) colv[r] = t * RPL + 1 + r;
        int prev_up = t * RPL;

        const int* wptr = words + b * SEQ;
        int p0 = 0, p1 = 0;
        if (t == 0) {
            p0 = __hip_atomic_load(&wptr[0], __ATOMIC_RELAXED, __HIP_MEMORY_SCOPE_AGENT);
            p1 = __hip_atomic_load(&wptr[1], __ATOMIC_RELAXED, __HIP_MEMORY_SCOPE_AGENT);
        }

        int w_prev = 0;
        const int NSTEP = SEQ + 63;              // 575
        for (int s = 1; s <= NSTEP; ++s) {
            int w_this = __shfl_up(w_prev, 1, 64);
            if (t == 0 && s <= SEQ) {
                while (p0 == 0) {
                    __builtin_amdgcn_s_sleep(2);
                    p0 = __hip_atomic_load(&wptr[s - 1], __ATOMIC_RELAXED,
                                           __HIP_MEMORY_SCOPE_AGENT);
                }
                w_this = p0;
                p0 = p1;
                p1 = (s + 1 <= SEQ)
                   ? __hip_atomic_load(&wptr[s + 1], __ATOMIC_RELAXED,
                                       __HIP_MEMORY_SCOPE_AGENT)
                   : 0;
            }

            int up_in = __shfl_up(colv[RPL - 1], 1, 64);
            if (t == 0) up_in = s;               // E[0][j] = j

            const int j = s - t;
            if (j >= 1 && j <= SEQ) {
                int mp[RPL];
                mp[0] = min(colv[0], prev_up - (myt[0] == w_this ? 1 : 0)) + 1;
                #pragma unroll
                for (int r = 1; r < RPL; ++r)
                    mp[r] = min(colv[r], colv[r - 1] - (myt[r] == w_this ? 1 : 0)) + 1;
                int u = up_in;
                #pragma unroll
                for (int r = 0; r < RPL; ++r) {
                    u = min(u + 1, mp[r]);
                    colv[r] = u;
                }
                prev_up = up_in;
            }
            w_prev = w_this;
        }

        if (t == 63)
            atomicAdd(out, (float)colv[RPL - 1] * (1.0f / ((float)BATCH * (float)SEQ)));
        return;
    }

    // ================= argmax producer =================
    const int wgid = (blockIdx.x - NED) * 4 + wid;        // 0..4095
    #pragma unroll
    for (int kq = 0; kq < 2; ++kq) {
        const int l   = kq * 4096 + wgid;                 // j-major row index
        const int row = (l & 15) * SEQ + (l >> 4);        // b*512 + j
        const floatx4* base4 = (const floatx4*)(logits + (size_t)row * VOCAB);

        const int shift = (row * 53) % NBLK;              // channel-decorrelating start

        float best = -INFINITY;
        int bestIdx = 0x7FFFFFFF;

        #pragma unroll 5
        for (int it = 0; it < NBLK; ++it) {
            int blk = it + shift;
            if (blk >= NBLK) blk -= NBLK;                 // circular wrap
            const int k = blk * 64 + lane;
            floatx4 v = __builtin_nontemporal_load(base4 + k);
            const int i0 = k * 4;
            if (v.x > best || (v.x == best && i0     < bestIdx)) { best = v.x; bestIdx = i0;     }
            if (v.y > best || (v.y == best && i0 + 1 < bestIdx)) { best = v.y; bestIdx = i0 + 1; }
            if (v.z > best || (v.z == best && i0 + 2 < bestIdx)) { best = v.z; bestIdx = i0 + 2; }
            if (v.w > best || (v.w == best && i0 + 3 < bestIdx)) { best = v.w; bestIdx = i0 + 3; }
        }

        for (int off = 32; off > 0; off >>= 1) {
            float ov = __shfl_down(best, off, 64);
            int   oi = __shfl_down(bestIdx, off, 64);
            if (ov > best || (ov == best && oi < bestIdx)) { best = ov; bestIdx = oi; }
        }
        if (lane == 0)
            __hip_atomic_store(&words[row], bestIdx + 1, __ATOMIC_RELAXED,
                               __HIP_MEMORY_SCOPE_AGENT);
    }
}

extern "C" void kernel_launch(void* const* d_in, const int* in_sizes, int n_in,
                              void* d_out, int out_size, void* d_ws, size_t ws_size,
                              hipStream_t stream) {
    const float* logits = (const float*)d_in[0];
    const int*   target = (const int*)d_in[1];

    int* words = (int*)d_ws;       // BATCH*SEQ ints (0 = not ready, else idx+1)
    float* out = (float*)d_out;

    init_kernel<<<(BATCH * SEQ + 255) / 256, 256, 0, stream>>>(words, out);
    fused_kernel<<<NED + NAMX, 256, 0, stream>>>(logits, target, words, out);
}

// Round 12
// 251.712 us; speedup vs baseline: 1.2795x; 1.2795x over previous
//
#include <hip/hip_runtime.h>
#include <math.h>

#define VOCAB 32000
#define BATCH 16
#define SEQ   512
#define RPL   8      // DP rows per lane in editdist
#define PINROWS 1408 // rows read with caching loads (180 MB < 256 MB L3)

typedef float floatx4 __attribute__((ext_vector_type(4)));

// ---------------------------------------------------------------------------
// Kernel 1: argmax over vocab axis. One WAVE per (b,s) row; 4 waves/block.
// Each wave streams a contiguous 128 KB row. Rows < PINROWS use caching
// loads, the rest nontemporal (R6 A/B: nt = -22us; R10: hybrid +2.5us free).
// Wave-per-row linear order is the best of 6 tested configs (~5.0 TB/s,
// the empirical nt-read ceiling for this access shape on this part).
// Fusion with editdist regressed twice (R5: -56us, R11: -71us) — dead end.
// First-occurrence tie-break matches jnp.argmax. Zeroes out[0] for the
// fused finalize (safe: kernels serialize on the stream).
// ---------------------------------------------------------------------------
__global__ __launch_bounds__(256) void argmax_kernel(const float* __restrict__ logits,
                                                     int* __restrict__ words,
                                                     float* __restrict__ out) {
    if (blockIdx.x == 0 && threadIdx.x == 0) out[0] = 0.0f;

    const int wid  = threadIdx.x >> 6;          // wave in block: 0..3
    const int lane = threadIdx.x & 63;
    const int row  = blockIdx.x * 4 + wid;      // 0 .. BATCH*SEQ-1
    const floatx4* base4 = (const floatx4*)(logits + (size_t)row * VOCAB);

    float best = -INFINITY;
    int bestIdx = 0x7FFFFFFF;

    if (row < PINROWS) {
        // caching loads: allocate in L2/L3
        #pragma unroll 5
        for (int k = lane; k < VOCAB / 4; k += 64) {
            floatx4 v = base4[k];
            int i0 = k * 4;
            if (v.x > best) { best = v.x; bestIdx = i0;     }
            if (v.y > best) { best = v.y; bestIdx = i0 + 1; }
            if (v.z > best) { best = v.z; bestIdx = i0 + 2; }
            if (v.w > best) { best = v.w; bestIdx = i0 + 3; }
        }
    } else {
        // nontemporal: stream past the caches
        #pragma unroll 5
        for (int k = lane; k < VOCAB / 4; k += 64) {
            floatx4 v = __builtin_nontemporal_load(base4 + k);
            int i0 = k * 4;
            if (v.x > best) { best = v.x; bestIdx = i0;     }
            if (v.y > best) { best = v.y; bestIdx = i0 + 1; }
            if (v.z > best) { best = v.z; bestIdx = i0 + 2; }
            if (v.w > best) { best = v.w; bestIdx = i0 + 3; }
        }
    }

    // 64-lane reduction, lower-index tie-break
    for (int off = 32; off > 0; off >>= 1) {
        float ov = __shfl_down(best, off, 64);
        int   oi = __shfl_down(bestIdx, off, 64);
        if (ov > best || (ov == best && oi < bestIdx)) { best = ov; bestIdx = oi; }
    }
    if (lane == 0) words[row] = bestIdx;
}

// ---------------------------------------------------------------------------
// Kernel 2: Levenshtein DP — single-wave staggered column march, no barriers.
// Lane t owns DP rows t*8+1..t*8+8 in registers; at step s it processes
// column j = s - t. Off-chain precompute mp[r] = min(left, diag-eq)+1 keeps
// the serial chain at 2 ops/row: u = min(u+1, mp[r]).
// Fused finalize: lane 63 atomicAdds dist/(B*S) into out[0] (exact dyadic
// rationals -> order-independent, deterministic).
// ---------------------------------------------------------------------------
__global__ __launch_bounds__(64) void editdist_kernel(const int* __restrict__ words,
                                                      const int* __restrict__ target,
                                                      float* __restrict__ out) {
    const int b = blockIdx.x;
    const int t = threadIdx.x;      // lane 0..63

    __shared__ int s_tg[SEQ];
    #pragma unroll
    for (int k = 0; k < RPL; ++k)
        s_tg[t + 64 * k] = target[b * SEQ + t + 64 * k];
    __syncthreads();

    int myw[RPL];
    #pragma unroll
    for (int r = 0; r < RPL; ++r)
        myw[r] = words[b * SEQ + t * RPL + r];

    int colv[RPL];
    #pragma unroll
    for (int r = 0; r < RPL; ++r) colv[r] = t * RPL + 1 + r;
    int prev_up = t * RPL;

    const int NSTEP = SEQ + 63;     // 575
    for (int s = 1; s <= NSTEP; ++s) {
        int up_in = __shfl_up(colv[RPL - 1], 1, 64);   // D[t*8][j] from lane t-1
        const int j = s - t;
        if (t == 0) up_in = s;                          // D[0][j] = j
        if (j >= 1 && j <= SEQ) {
            const int tgj = s_tg[j - 1];
            int mp[RPL];
            mp[0] = min(colv[0], prev_up - (myw[0] == tgj ? 1 : 0)) + 1;
            #pragma unroll
            for (int r = 1; r < RPL; ++r)
                mp[r] = min(colv[r], colv[r - 1] - (myw[r] == tgj ? 1 : 0)) + 1;
            int u = up_in;
            #pragma unroll
            for (int r = 0; r < RPL; ++r) {
                u = min(u + 1, mp[r]);
                colv[r] = u;
            }
            prev_up = up_in;
        }
    }

    if (t == 63)
        atomicAdd(out, (float)colv[RPL - 1] * (1.0f / ((float)BATCH * (float)SEQ)));
}

extern "C" void kernel_launch(void* const* d_in, const int* in_sizes, int n_in,
                              void* d_out, int out_size, void* d_ws, size_t ws_size,
                              hipStream_t stream) {
    const float* logits = (const float*)d_in[0];
    const int*   target = (const int*)d_in[1];

    int* words = (int*)d_ws;   // BATCH*SEQ ints
    float* out = (float*)d_out;

    argmax_kernel<<<BATCH * SEQ / 4, 256, 0, stream>>>(logits, words, out);
    editdist_kernel<<<BATCH, 64, 0, stream>>>(words, target, out);
}